// Round 1
// baseline (797.951 us; speedup 1.0000x reference)
//
#include <hip/hip_runtime.h>

// MultiHeadAttention (faithful-to-bug variant):
//   Qt[b,n,h,k] = sum_d x[b,n,d] * qp[k,h,d]        (mislabeled-einsum swap)
//   K [b,m,h,k] = sum_d x[b,m,d] * kp[h,k,d]
//   V [b,m,h,v] = sum_d x[b,m,d] * vp[h,v,d]
//   S [b,h,n,m] = sum_k Qt[b,n,h,k] * K[b,m,h,k]
//   A = softmax over n (axis=1!)  -> per-column normalization of S
//   O [b,n,h,v] = sum_m A * V
//   out[b,n,d]  = sum_{h,v} O * op[d,h,v]
//
// Round 0: all-f32 correctness baseline. Tiled vector-ALU GEMMs; softmax via
// column-sum pass (no max subtraction: |scale*S| < ~4 for these inputs, exp
// cannot overflow f32) + fused recompute pass.

namespace {
constexpr int B = 2;
constexpr int N = 2048;
constexpr int D = 1024;
constexpr int H = 16;
constexpr int KD = 16;
constexpr int VD = 64;
constexpr float SCALE = 0.25f;  // 1/sqrt(16)

// workspace layout (float offsets)
constexpr size_t WS_QT = 0;                               // [B][H][N][KD]
constexpr size_t WS_KH = WS_QT + (size_t)B * H * N * KD;  // [B][H][N][KD]
constexpr size_t WS_VH = WS_KH + (size_t)B * H * N * KD;  // [B][H][N][VD]
constexpr size_t WS_ZI = WS_VH + (size_t)B * H * N * VD;  // [B][H][N]  (1/colsum)
constexpr size_t WS_OH = WS_ZI + (size_t)B * H * N;       // [B][H][N][VD]
}  // namespace

// ---------------------------------------------------------------------------
// Kernel 1: QKV projection. C[4096 x 1536] = X[4096 x 1024] @ W^T, where the
// 1536 output columns are [Qt(256) | K(256) | V(1024)] with per-column weight
// rows resolved from the three projection tensors (Qt uses the swapped qp
// indexing). 64x64 tiles, KT=16, 4x4 micro-tile per thread.
// ---------------------------------------------------------------------------
__global__ __launch_bounds__(256) void k_qkv(
    const float* __restrict__ x, const float* __restrict__ qp,
    const float* __restrict__ kp, const float* __restrict__ vp,
    float* __restrict__ Qt, float* __restrict__ Kh, float* __restrict__ Vh) {
  __shared__ float Xs[64][17];                 // +1 pad: kill 4-way conflicts
  __shared__ __align__(16) float Ws[16][68];   // 68*4B = 17*16B: float4-aligned rows
  const int tid = threadIdx.x;
  const int tx = tid & 15, ty = tid >> 4;
  const int c0 = blockIdx.x * 64;  // output-column tile base (0..1535)
  const int r0 = blockIdx.y * 64;  // bn-row tile base

  const int lr = tid >> 2;         // 0..63: row/col this thread loads
  const int l4 = (tid & 3) * 4;    // 0,4,8,12: k-offset this thread loads

  // resolve weight row pointer for the column this thread stages
  const int C = c0 + lr;
  const float* wrow;
  if (C < 256) {
    int h = C >> 4, k = C & 15;
    wrow = qp + (size_t)(k * KD + h) * D;  // swapped: Qt col (h,k) <- qp[k][h][:]
  } else if (C < 512) {
    int cc = C - 256;
    int h = cc >> 4, k = cc & 15;
    wrow = kp + (size_t)(h * KD + k) * D;
  } else {
    int cc = C - 512;
    int h = cc >> 6, v = cc & 63;
    wrow = vp + (size_t)(h * VD + v) * D;
  }
  const float* xrow = x + (size_t)(r0 + lr) * D;

  float acc[4][4] = {};
  for (int k0 = 0; k0 < D; k0 += 16) {
    float4 gx = *reinterpret_cast<const float4*>(xrow + k0 + l4);
    float4 gw = *reinterpret_cast<const float4*>(wrow + k0 + l4);
    __syncthreads();
    Xs[lr][l4 + 0] = gx.x; Xs[lr][l4 + 1] = gx.y;
    Xs[lr][l4 + 2] = gx.z; Xs[lr][l4 + 3] = gx.w;
    Ws[l4 + 0][lr] = gw.x; Ws[l4 + 1][lr] = gw.y;  // transpose into LDS
    Ws[l4 + 2][lr] = gw.z; Ws[l4 + 3][lr] = gw.w;
    __syncthreads();
#pragma unroll
    for (int kk = 0; kk < 16; ++kk) {
      float a0 = Xs[ty * 4 + 0][kk];
      float a1 = Xs[ty * 4 + 1][kk];
      float a2 = Xs[ty * 4 + 2][kk];
      float a3 = Xs[ty * 4 + 3][kk];
      float4 bv = *reinterpret_cast<const float4*>(&Ws[kk][tx * 4]);
      acc[0][0] += a0 * bv.x; acc[0][1] += a0 * bv.y; acc[0][2] += a0 * bv.z; acc[0][3] += a0 * bv.w;
      acc[1][0] += a1 * bv.x; acc[1][1] += a1 * bv.y; acc[1][2] += a1 * bv.z; acc[1][3] += a1 * bv.w;
      acc[2][0] += a2 * bv.x; acc[2][1] += a2 * bv.y; acc[2][2] += a2 * bv.z; acc[2][3] += a2 * bv.w;
      acc[3][0] += a3 * bv.x; acc[3][1] += a3 * bv.y; acc[3][2] += a3 * bv.z; acc[3][3] += a3 * bv.w;
    }
  }
  // epilogue: 4 consecutive output cols per thread -> one float4 per row
  const int Cc = c0 + tx * 4;
#pragma unroll
  for (int i = 0; i < 4; ++i) {
    int row = r0 + ty * 4 + i;
    int b = row >> 11, n = row & (N - 1);
    float4 o = make_float4(acc[i][0], acc[i][1], acc[i][2], acc[i][3]);
    if (Cc < 256) {
      int h = Cc >> 4, k = Cc & 15;
      *reinterpret_cast<float4*>(&Qt[(((size_t)b * H + h) * N + n) * KD + k]) = o;
    } else if (Cc < 512) {
      int cc = Cc - 256;
      int h = cc >> 4, k = cc & 15;
      *reinterpret_cast<float4*>(&Kh[(((size_t)b * H + h) * N + n) * KD + k]) = o;
    } else {
      int cc = Cc - 512;
      int h = cc >> 6, v = cc & 63;
      *reinterpret_cast<float4*>(&Vh[(((size_t)b * H + h) * N + n) * VD + v]) = o;
    }
  }
}

// ---------------------------------------------------------------------------
// Kernel 2: per-column softmax denominator. For each (b,h,m):
//   Z = sum_n exp(scale * S[n,m]);  store 1/Z.
// Block: one (b,h), 64 columns; 4 wave-slices each own 512 n-rows.
// ---------------------------------------------------------------------------
__global__ __launch_bounds__(256) void k_colsum(const float* __restrict__ Qt,
                                                const float* __restrict__ Kh,
                                                float* __restrict__ Zi) {
  const int m0 = blockIdx.x * 64;
  const int bh = blockIdx.z * H + blockIdx.y;
  const float* qbase = Qt + (size_t)bh * N * KD;
  const float* kbase = Kh + (size_t)bh * N * KD;
  __shared__ __align__(16) float QtL[128][20];  // 20*4B = 5*16B aligned rows
  __shared__ float Zs[4][64];
  const int tid = threadIdx.x;
  const int col = tid & 63;   // one m-column per lane (whole wave = 64 cols)
  const int slice = tid >> 6; // which quarter of the n-range

  // this thread's K row, held in registers for the whole kernel
  const float* krow = kbase + (size_t)(m0 + col) * KD;
  float4 kr0 = *reinterpret_cast<const float4*>(krow + 0);
  float4 kr1 = *reinterpret_cast<const float4*>(krow + 4);
  float4 kr2 = *reinterpret_cast<const float4*>(krow + 8);
  float4 kr3 = *reinterpret_cast<const float4*>(krow + 12);

  float z = 0.f;
  for (int nt = 0; nt < N; nt += 128) {
    __syncthreads();
    int r = tid >> 1, k8 = (tid & 1) * 8;
    float4 g0 = *reinterpret_cast<const float4*>(&qbase[(size_t)(nt + r) * KD + k8]);
    float4 g1 = *reinterpret_cast<const float4*>(&qbase[(size_t)(nt + r) * KD + k8 + 4]);
    *reinterpret_cast<float4*>(&QtL[r][k8]) = g0;
    *reinterpret_cast<float4*>(&QtL[r][k8 + 4]) = g1;
    __syncthreads();
#pragma unroll 4
    for (int rr = 0; rr < 32; ++rr) {
      int r2 = slice * 32 + rr;
      float4 q0 = *reinterpret_cast<const float4*>(&QtL[r2][0]);
      float4 q1 = *reinterpret_cast<const float4*>(&QtL[r2][4]);
      float4 q2 = *reinterpret_cast<const float4*>(&QtL[r2][8]);
      float4 q3 = *reinterpret_cast<const float4*>(&QtL[r2][12]);
      float s = q0.x * kr0.x + q0.y * kr0.y + q0.z * kr0.z + q0.w * kr0.w
              + q1.x * kr1.x + q1.y * kr1.y + q1.z * kr1.z + q1.w * kr1.w
              + q2.x * kr2.x + q2.y * kr2.y + q2.z * kr2.z + q2.w * kr2.w
              + q3.x * kr3.x + q3.y * kr3.y + q3.z * kr3.z + q3.w * kr3.w;
      z += __expf(s * SCALE);
    }
  }
  Zs[slice][col] = z;
  __syncthreads();
  if (slice == 0) {
    float Zt = Zs[0][col] + Zs[1][col] + Zs[2][col] + Zs[3][col];
    Zi[(size_t)bh * N + m0 + col] = 1.0f / Zt;
  }
}

// ---------------------------------------------------------------------------
// Kernel 3: fused attention output. Per (b,h), n-tile of 64 rows:
//   O[n,v] = sum_m exp(scale*S[n,m]) * Zi[m] * V[m,v]
// Recomputes S tile-wise (phase A, cooperative into LDS) then GEMM-accumulates
// P @ V (phase B, 4x4 micro-tile per thread).
// ---------------------------------------------------------------------------
__global__ __launch_bounds__(256) void k_attn(
    const float* __restrict__ Qt, const float* __restrict__ Kh,
    const float* __restrict__ Vh, const float* __restrict__ Zi,
    float* __restrict__ Oh) {
  const int n0 = blockIdx.x * 64;
  const int bh = blockIdx.z * H + blockIdx.y;
  const float* qbase = Qt + (size_t)bh * N * KD;
  const float* kbase = Kh + (size_t)bh * N * KD;
  const float* vbase = Vh + (size_t)bh * N * VD;
  const float* zbase = Zi + (size_t)bh * N;
  __shared__ float QtL[64][17];
  __shared__ __align__(16) float KL[16][20];
  __shared__ __align__(16) float VL[16][68];
  __shared__ __align__(16) float PL[64][20];
  __shared__ float Iv[16];
  const int tid = threadIdx.x;
  const int tx = tid & 15, ty = tid >> 4;

  // stage this block's 64 Q rows once, then hoist 4 rows into registers
  {
    int r = tid >> 2, k4 = (tid & 3) * 4;
    float4 g = *reinterpret_cast<const float4*>(&qbase[(size_t)(n0 + r) * KD + k4]);
    QtL[r][k4 + 0] = g.x; QtL[r][k4 + 1] = g.y;
    QtL[r][k4 + 2] = g.z; QtL[r][k4 + 3] = g.w;
  }
  __syncthreads();
  float qreg[4][16];
#pragma unroll
  for (int i = 0; i < 4; ++i)
#pragma unroll
    for (int k = 0; k < 16; ++k) qreg[i][k] = QtL[ty * 4 + i][k];

  float acc[4][4] = {};
  for (int m0 = 0; m0 < N; m0 += 16) {
    __syncthreads();  // previous iteration's phase-B reads complete
    if (tid < 64) {
      int r = tid >> 2, k4 = (tid & 3) * 4;
      float4 g = *reinterpret_cast<const float4*>(&kbase[(size_t)(m0 + r) * KD + k4]);
      *reinterpret_cast<float4*>(&KL[r][k4]) = g;
    } else if (tid < 80) {
      Iv[tid - 64] = zbase[m0 + (tid - 64)];
    }
    {
      int r = tid >> 4, v4 = (tid & 15) * 4;
      float4 g = *reinterpret_cast<const float4*>(&vbase[(size_t)(m0 + r) * VD + v4]);
      *reinterpret_cast<float4*>(&VL[r][v4]) = g;
    }
    __syncthreads();
    // phase A: this thread computes P[ty*4+i][tx], i=0..3
    {
      float4 k0v = *reinterpret_cast<const float4*>(&KL[tx][0]);
      float4 k1v = *reinterpret_cast<const float4*>(&KL[tx][4]);
      float4 k2v = *reinterpret_cast<const float4*>(&KL[tx][8]);
      float4 k3v = *reinterpret_cast<const float4*>(&KL[tx][12]);
      float iv = Iv[tx];
#pragma unroll
      for (int i = 0; i < 4; ++i) {
        float s = qreg[i][0]  * k0v.x + qreg[i][1]  * k0v.y + qreg[i][2]  * k0v.z + qreg[i][3]  * k0v.w
                + qreg[i][4]  * k1v.x + qreg[i][5]  * k1v.y + qreg[i][6]  * k1v.z + qreg[i][7]  * k1v.w
                + qreg[i][8]  * k2v.x + qreg[i][9]  * k2v.y + qreg[i][10] * k2v.z + qreg[i][11] * k2v.w
                + qreg[i][12] * k3v.x + qreg[i][13] * k3v.y + qreg[i][14] * k3v.z + qreg[i][15] * k3v.w;
        PL[ty * 4 + i][tx] = __expf(s * SCALE) * iv;
      }
    }
    __syncthreads();
    // phase B: acc += P[64x16] @ V[16x64]
#pragma unroll
    for (int mm = 0; mm < 16; ++mm) {
      float a0 = PL[ty * 4 + 0][mm];
      float a1 = PL[ty * 4 + 1][mm];
      float a2 = PL[ty * 4 + 2][mm];
      float a3 = PL[ty * 4 + 3][mm];
      float4 bv = *reinterpret_cast<const float4*>(&VL[mm][tx * 4]);
      acc[0][0] += a0 * bv.x; acc[0][1] += a0 * bv.y; acc[0][2] += a0 * bv.z; acc[0][3] += a0 * bv.w;
      acc[1][0] += a1 * bv.x; acc[1][1] += a1 * bv.y; acc[1][2] += a1 * bv.z; acc[1][3] += a1 * bv.w;
      acc[2][0] += a2 * bv.x; acc[2][1] += a2 * bv.y; acc[2][2] += a2 * bv.z; acc[2][3] += a2 * bv.w;
      acc[3][0] += a3 * bv.x; acc[3][1] += a3 * bv.y; acc[3][2] += a3 * bv.z; acc[3][3] += a3 * bv.w;
    }
  }
#pragma unroll
  for (int i = 0; i < 4; ++i) {
    float4 o = make_float4(acc[i][0], acc[i][1], acc[i][2], acc[i][3]);
    *reinterpret_cast<float4*>(&Oh[((size_t)bh * N + n0 + ty * 4 + i) * VD + tx * 4]) = o;
  }
}

// ---------------------------------------------------------------------------
// Kernel 4: output projection. out[bn, d] = sum_{hv} O[b,h,n,v] * op[d, h*64+v]
// Same tiled-GEMM structure as kernel 1.
// ---------------------------------------------------------------------------
__global__ __launch_bounds__(256) void k_out(const float* __restrict__ Oh,
                                             const float* __restrict__ op,
                                             float* __restrict__ out) {
  __shared__ float As[64][17];
  __shared__ __align__(16) float Ws[16][68];
  const int tid = threadIdx.x;
  const int tx = tid & 15, ty = tid >> 4;
  const int d0 = blockIdx.x * 64;
  const int r0 = blockIdx.y * 64;
  const int lr = tid >> 2, l4 = (tid & 3) * 4;

  const int arow = r0 + lr;
  const int ab = arow >> 11, an = arow & (N - 1);
  const float* obase = Oh + (size_t)ab * H * N * VD;
  const float* wrow = op + (size_t)(d0 + lr) * (H * VD);

  float acc[4][4] = {};
  for (int k0 = 0; k0 < H * VD; k0 += 16) {
    int hv = k0 + l4;
    int h = hv >> 6, v = hv & 63;  // 16-wide K-tile never crosses a head
    float4 ga = *reinterpret_cast<const float4*>(&obase[((size_t)h * N + an) * VD + v]);
    float4 gw = *reinterpret_cast<const float4*>(&wrow[k0 + l4]);
    __syncthreads();
    As[lr][l4 + 0] = ga.x; As[lr][l4 + 1] = ga.y;
    As[lr][l4 + 2] = ga.z; As[lr][l4 + 3] = ga.w;
    Ws[l4 + 0][lr] = gw.x; Ws[l4 + 1][lr] = gw.y;
    Ws[l4 + 2][lr] = gw.z; Ws[l4 + 3][lr] = gw.w;
    __syncthreads();
#pragma unroll
    for (int kk = 0; kk < 16; ++kk) {
      float a0 = As[ty * 4 + 0][kk];
      float a1 = As[ty * 4 + 1][kk];
      float a2 = As[ty * 4 + 2][kk];
      float a3 = As[ty * 4 + 3][kk];
      float4 bv = *reinterpret_cast<const float4*>(&Ws[kk][tx * 4]);
      acc[0][0] += a0 * bv.x; acc[0][1] += a0 * bv.y; acc[0][2] += a0 * bv.z; acc[0][3] += a0 * bv.w;
      acc[1][0] += a1 * bv.x; acc[1][1] += a1 * bv.y; acc[1][2] += a1 * bv.z; acc[1][3] += a1 * bv.w;
      acc[2][0] += a2 * bv.x; acc[2][1] += a2 * bv.y; acc[2][2] += a2 * bv.z; acc[2][3] += a2 * bv.w;
      acc[3][0] += a3 * bv.x; acc[3][1] += a3 * bv.y; acc[3][2] += a3 * bv.z; acc[3][3] += a3 * bv.w;
    }
  }
#pragma unroll
  for (int i = 0; i < 4; ++i) {
    int row = r0 + ty * 4 + i;
    float4 o = make_float4(acc[i][0], acc[i][1], acc[i][2], acc[i][3]);
    *reinterpret_cast<float4*>(&out[(size_t)row * D + d0 + tx * 4]) = o;
  }
}

// ---------------------------------------------------------------------------
extern "C" void kernel_launch(void* const* d_in, const int* in_sizes, int n_in,
                              void* d_out, int out_size, void* d_ws, size_t ws_size,
                              hipStream_t stream) {
  (void)in_sizes; (void)n_in; (void)out_size; (void)ws_size;
  const float* x  = (const float*)d_in[0];
  const float* qp = (const float*)d_in[1];
  const float* kp = (const float*)d_in[2];
  const float* vp = (const float*)d_in[3];
  const float* op = (const float*)d_in[4];
  float* out = (float*)d_out;
  float* ws = (float*)d_ws;

  float* Qt = ws + WS_QT;
  float* Kh = ws + WS_KH;
  float* Vh = ws + WS_VH;
  float* Zi = ws + WS_ZI;
  float* Oh = ws + WS_OH;

  // 1) QKV projection (writes head-major Qt/K/V)
  k_qkv<<<dim3(1536 / 64, (B * N) / 64), 256, 0, stream>>>(x, qp, kp, vp, Qt, Kh, Vh);
  // 2) softmax column sums (softmax is over the QUERY axis n)
  k_colsum<<<dim3(N / 64, H, B), 256, 0, stream>>>(Qt, Kh, Zi);
  // 3) fused recompute + P@V
  k_attn<<<dim3(N / 64, H, B), 256, 0, stream>>>(Qt, Kh, Vh, Zi, Oh);
  // 4) output projection
  k_out<<<dim3(D / 64, (B * N) / 64), 256, 0, stream>>>(Oh, op, out);
}

// Round 2
// 151.447 us; speedup vs baseline: 5.2689x; 5.2689x over previous
//
#include <hip/hip_runtime.h>

// MultiHeadAttention (faithful-to-bug variant), round 1: bf16 MFMA everywhere.
//   Qt[b,n,h,k] = sum_d x[b,n,d] * qp[k,h,d]        (mislabeled-einsum swap)
//   K [b,m,h,k] = sum_d x[b,m,d] * kp[h,k,d]
//   V [b,m,h,v] = sum_d x[b,m,d] * vp[h,v,d]
//   S [b,h,n,m] = sum_k Qt*K ;  A = softmax over n (axis=1 -> column softmax)
//   O [b,n,h,v] = sum_m A * V ;  out = sum_{h,v} O * op[d,h,v]
//
// Pipeline: k_cvt (f32->bf16 pack) -> k_qkv (MFMA GEMM, writes Qt/Kh head-major
// and V TRANSPOSED per head) -> k_colsum (MFMA S^T + exp colsum -> Zi=1/Z) ->
// k_attn (MFMA S^T -> P^T in-register -> PV as O^T = V^T P^T) -> k_out (MFMA).

typedef float f32x4 __attribute__((ext_vector_type(4)));
typedef short s16x4 __attribute__((ext_vector_type(4)));
typedef short s16x8 __attribute__((ext_vector_type(8)));
typedef unsigned short u16;

namespace {
constexpr float SCALE = 0.25f;  // 1/sqrt(16)

// workspace byte offsets (all 16B aligned)
constexpr size_t OFF_XB = 0;                                  // xb [4096][1024] bf16
constexpr size_t OFF_WB = OFF_XB + (size_t)4096 * 1024 * 2;   // Wb [1536][1024] bf16
constexpr size_t OFF_WO = OFF_WB + (size_t)1536 * 1024 * 2;   // wo [1024][1024] bf16
constexpr size_t OFF_QT = OFF_WO + (size_t)1024 * 1024 * 2;   // Qt [2][16][2048][16] bf16
constexpr size_t OFF_KH = OFF_QT + (size_t)2 * 16 * 2048 * 16 * 2;
constexpr size_t OFF_VT = OFF_KH + (size_t)2 * 16 * 2048 * 16 * 2;  // Vt [2][16][64][2048] bf16
constexpr size_t OFF_ZI = OFF_VT + (size_t)2 * 16 * 64 * 2048 * 2;  // Zi [2][16][2048] f32
constexpr size_t OFF_OH = OFF_ZI + (size_t)2 * 16 * 2048 * 4;       // Oh [2][16][2048][64] bf16
}  // namespace

__device__ __forceinline__ u16 f2bf(float f) {  // RNE f32->bf16
  union { float f; unsigned u; } v; v.f = f;
  return (u16)((v.u + 0x7FFF + ((v.u >> 16) & 1)) >> 16);
}

__device__ __forceinline__ f32x4 mfma16(s16x4 a, s16x4 b, f32x4 c) {
#if __has_builtin(__builtin_amdgcn_mfma_f32_16x16x16_bf16)
  return __builtin_amdgcn_mfma_f32_16x16x16_bf16(a, b, c, 0, 0, 0);
#elif __has_builtin(__builtin_amdgcn_mfma_f32_16x16x16bf16_1k)
  return __builtin_amdgcn_mfma_f32_16x16x16bf16_1k(a, b, c, 0, 0, 0);
#else
  f32x4 d;
  asm volatile("v_mfma_f32_16x16x16_bf16 %0, %1, %2, %3"
               : "=v"(d) : "v"(a), "v"(b), "v"(c));
  return d;
#endif
}

// ---------------------------------------------------------------------------
// k_cvt: f32 -> bf16 conversion + weight packing.
//   xb[r][c] = x ; Wb rows: [0,256)=qp PERMUTED (row h*16+k <- qp row k*16+h),
//   [256,512)=kp, [512,1536)=vp ; wo = op (already [d][h*64+v] row-major).
// ---------------------------------------------------------------------------
__global__ __launch_bounds__(256) void k_cvt(
    const float* __restrict__ x, const float* __restrict__ qp,
    const float* __restrict__ kp, const float* __restrict__ vp,
    const float* __restrict__ op, u16* __restrict__ xb,
    u16* __restrict__ Wb, u16* __restrict__ wo) {
  const int c = blockIdx.x * 256 + threadIdx.x;  // 8-element chunk id
  const int XC = (4096 * 1024) / 8, WC = (1536 * 1024) / 8, OC = (1024 * 1024) / 8;
  const float* src; u16* dst;
  if (c < XC) {
    src = x + (size_t)c * 8; dst = xb + (size_t)c * 8;
  } else if (c < XC + WC) {
    const int cc = c - XC;
    const int row = cc >> 7, col = cc & 127;  // 128 chunks per 1024-row
    if (row < 256) {
      const int h = row >> 4, k = row & 15;
      src = qp + (size_t)(k * 16 + h) * 1024 + col * 8;  // swapped einsum
    } else if (row < 512) {
      src = kp + (size_t)(row - 256) * 1024 + col * 8;
    } else {
      src = vp + (size_t)(row - 512) * 1024 + col * 8;
    }
    dst = Wb + (size_t)cc * 8;
  } else if (c < XC + WC + OC) {
    const int cc = c - XC - WC;
    src = op + (size_t)cc * 8; dst = wo + (size_t)cc * 8;
  } else {
    return;
  }
  float4 lo = *(const float4*)(src);
  float4 hi = *(const float4*)(src + 4);
  union { s16x8 v; u16 e[8]; } o;
  o.e[0] = f2bf(lo.x); o.e[1] = f2bf(lo.y); o.e[2] = f2bf(lo.z); o.e[3] = f2bf(lo.w);
  o.e[4] = f2bf(hi.x); o.e[5] = f2bf(hi.y); o.e[6] = f2bf(hi.z); o.e[7] = f2bf(hi.w);
  *(s16x8*)dst = o.v;
}

// ---------------------------------------------------------------------------
// k_qkv: C[4096 x 1536] = xb @ Wb^T via mfma_f32_16x16x32_bf16.
// Tile 128 rows x 64 cols, BK=64, 4 waves (2x2), 64x32 per wave.
// Epilogue scatters: cols [0,256)->Qt, [256,512)->Kh, [512,1536)->Vt (v-major!).
// ---------------------------------------------------------------------------
__global__ __launch_bounds__(256) void k_qkv(
    const u16* __restrict__ xb, const u16* __restrict__ Wb,
    u16* __restrict__ Qt, u16* __restrict__ Kh, u16* __restrict__ Vt) {
  __shared__ __align__(16) u16 As[128][72];  // 144B rows: 16B aligned, bank-balanced
  __shared__ __align__(16) u16 Bs[64][72];
  const int tid = threadIdx.x;
  const int wave = tid >> 6, lane = tid & 63;
  const int g = lane >> 4, r = lane & 15;
  const int wr = wave >> 1, wc = wave & 1;
  const int r0 = blockIdx.y * 128;
  const int c0 = blockIdx.x * 64;

  f32x4 acc[4][2];
#pragma unroll
  for (int mi = 0; mi < 4; ++mi)
#pragma unroll
    for (int ni = 0; ni < 2; ++ni)
#pragma unroll
      for (int i = 0; i < 4; ++i) acc[mi][ni][i] = 0.f;

  for (int k0 = 0; k0 < 1024; k0 += 64) {
    __syncthreads();
#pragma unroll
    for (int p = 0; p < 4; ++p) {  // A: 128x64 bf16 = 1024 16B-chunks
      const int ch = p * 256 + tid;
      const int row = ch >> 3, c8 = (ch & 7) * 8;
      s16x8 v = *(const s16x8*)(xb + (size_t)(r0 + row) * 1024 + k0 + c8);
      *(s16x8*)(&As[row][c8]) = v;
    }
#pragma unroll
    for (int p = 0; p < 2; ++p) {  // B: 64x64
      const int ch = p * 256 + tid;
      const int row = ch >> 3, c8 = (ch & 7) * 8;
      s16x8 v = *(const s16x8*)(Wb + (size_t)(c0 + row) * 1024 + k0 + c8);
      *(s16x8*)(&Bs[row][c8]) = v;
    }
    __syncthreads();
#pragma unroll
    for (int kf = 0; kf < 2; ++kf) {
      s16x8 a[4], b[2];
#pragma unroll
      for (int mi = 0; mi < 4; ++mi)
        a[mi] = *(const s16x8*)(&As[wr * 64 + mi * 16 + r][kf * 32 + g * 8]);
#pragma unroll
      for (int ni = 0; ni < 2; ++ni)
        b[ni] = *(const s16x8*)(&Bs[wc * 32 + ni * 16 + r][kf * 32 + g * 8]);
#pragma unroll
      for (int mi = 0; mi < 4; ++mi)
#pragma unroll
        for (int ni = 0; ni < 2; ++ni)
          acc[mi][ni] = __builtin_amdgcn_mfma_f32_16x16x32_bf16(a[mi], b[ni], acc[mi][ni], 0, 0, 0);
    }
  }
  // epilogue: D layout col=lane&15, row=g*4+i
#pragma unroll
  for (int ni = 0; ni < 2; ++ni) {
    const int c = c0 + wc * 32 + ni * 16 + r;
#pragma unroll
    for (int mi = 0; mi < 4; ++mi) {
      const int rowb = r0 + wr * 64 + mi * 16 + g * 4;
      const int b = rowb >> 11, n = rowb & 2047;
      if (c < 512) {
        u16* base = (c < 256) ? Qt : Kh;
        const int cc = c & 255;
        const int h = cc >> 4, kk = cc & 15;
        u16* p = base + (((size_t)b * 16 + h) * 2048 + n) * 16 + kk;
        p[0]  = f2bf(acc[mi][ni][0]);
        p[16] = f2bf(acc[mi][ni][1]);
        p[32] = f2bf(acc[mi][ni][2]);
        p[48] = f2bf(acc[mi][ni][3]);
      } else {
        const int cc = c - 512;
        const int h = cc >> 6, v = cc & 63;
        ushort4 o;
        o.x = f2bf(acc[mi][ni][0]); o.y = f2bf(acc[mi][ni][1]);
        o.z = f2bf(acc[mi][ni][2]); o.w = f2bf(acc[mi][ni][3]);
        *(ushort4*)(Vt + (((size_t)b * 16 + h) * 64 + v) * 2048 + n) = o;  // 4 consecutive n
      }
    }
  }
}

// ---------------------------------------------------------------------------
// k_colsum: Zi[b,h,m] = 1 / sum_n exp(SCALE * S[n,m]).
// Block = (m-tile of 64) x (b,h). S^T frags via mfma16(K, Qt); per-lane
// accumulate over n; butterfly-reduce over the 16 n-lanes; combine 4 waves.
// ---------------------------------------------------------------------------
__global__ __launch_bounds__(256) void k_colsum(
    const u16* __restrict__ Qt, const u16* __restrict__ Kh,
    float* __restrict__ Zi) {
  const int m0 = blockIdx.x * 64;
  const int bh = blockIdx.z * 16 + blockIdx.y;
  const u16* qbase = Qt + (size_t)bh * 2048 * 16;
  const u16* kbase = Kh + (size_t)bh * 2048 * 16;
  __shared__ __align__(16) u16 Ks[64][20];   // 40B rows: bank-spread
  __shared__ __align__(16) u16 Qs[128][20];
  __shared__ float Zp[4][64];
  const int tid = threadIdx.x;
  const int wave = tid >> 6, lane = tid & 63;
  const int g = lane >> 4, r = lane & 15;

  {  // stage K tile once: 64x16, one 8B chunk per thread
    const int row = tid >> 2, c4 = (tid & 3) * 4;
    *(s16x4*)(&Ks[row][c4]) = *(const s16x4*)(kbase + (size_t)(m0 + row) * 16 + c4);
  }
  __syncthreads();
  s16x4 afr[4];  // A = K: lane row m = mf*16+r, k = g*4..g*4+3
#pragma unroll
  for (int mf = 0; mf < 4; ++mf) afr[mf] = *(const s16x4*)(&Ks[mf * 16 + r][g * 4]);

  float z[4][4];  // [mf][i]: m = mf*16 + g*4 + i
#pragma unroll
  for (int mf = 0; mf < 4; ++mf)
#pragma unroll
    for (int i = 0; i < 4; ++i) z[mf][i] = 0.f;

  for (int n0 = 0; n0 < 2048; n0 += 128) {
    __syncthreads();
#pragma unroll
    for (int p = 0; p < 2; ++p) {  // stage Q tile 128x16
      const int ch = p * 256 + tid;
      const int row = ch >> 2, c4 = (ch & 3) * 4;
      *(s16x4*)(&Qs[row][c4]) = *(const s16x4*)(qbase + (size_t)(n0 + row) * 16 + c4);
    }
    __syncthreads();
#pragma unroll
    for (int nf = 0; nf < 2; ++nf) {
      s16x4 bfr = *(const s16x4*)(&Qs[wave * 32 + nf * 16 + r][g * 4]);
#pragma unroll
      for (int mf = 0; mf < 4; ++mf) {
        f32x4 st; st[0] = 0.f; st[1] = 0.f; st[2] = 0.f; st[3] = 0.f;
        st = mfma16(afr[mf], bfr, st);
#pragma unroll
        for (int i = 0; i < 4; ++i) z[mf][i] += __expf(st[i] * SCALE);
      }
    }
  }
  // reduce over the 16 n-lanes (cols) of each group
#pragma unroll
  for (int mf = 0; mf < 4; ++mf)
#pragma unroll
    for (int i = 0; i < 4; ++i) {
      float v = z[mf][i];
      v += __shfl_xor(v, 1); v += __shfl_xor(v, 2);
      v += __shfl_xor(v, 4); v += __shfl_xor(v, 8);
      z[mf][i] = v;
    }
  if (r == 0) {
#pragma unroll
    for (int mf = 0; mf < 4; ++mf)
#pragma unroll
      for (int i = 0; i < 4; ++i) Zp[wave][mf * 16 + g * 4 + i] = z[mf][i];
  }
  __syncthreads();
  if (tid < 64) {
    float s = Zp[0][tid] + Zp[1][tid] + Zp[2][tid] + Zp[3][tid];
    Zi[(size_t)bh * 2048 + m0 + tid] = 1.0f / s;
  }
}

// ---------------------------------------------------------------------------
// k_attn: per (b,h), 128 q-rows per block, sweep m in 64-tiles.
//   S^T = mfma16(K, Qt) ; P^T = exp(S^T*SCALE)*Zi[m] packed to bf16 in-register
//   (D-frag row pattern == 16x16x16 B-frag k pattern: no LDS round-trip);
//   O^T += mfma16(V^T, P^T). Output scattered to Oh[b][h][n][v] (n-major).
// ---------------------------------------------------------------------------
__global__ __launch_bounds__(256) void k_attn(
    const u16* __restrict__ Qt, const u16* __restrict__ Kh,
    const u16* __restrict__ Vt, const float* __restrict__ Zi,
    u16* __restrict__ Oh) {
  const int n0 = blockIdx.x * 128;
  const int bh = blockIdx.z * 16 + blockIdx.y;
  const u16* qbase = Qt + (size_t)bh * 2048 * 16;
  const u16* kbase = Kh + (size_t)bh * 2048 * 16;
  const u16* vbase = Vt + (size_t)bh * 64 * 2048;  // [v][n]
  const float* zbase = Zi + (size_t)bh * 2048;
  u16* obase = Oh + (size_t)bh * 2048 * 64;

  __shared__ __align__(16) u16 Ks[64][20];
  __shared__ __align__(16) u16 Vs[64][72];  // [v][m], 144B rows
  __shared__ float Zs[64];
  const int tid = threadIdx.x;
  const int wave = tid >> 6, lane = tid & 63;
  const int g = lane >> 4, r = lane & 15;

  // Qt B-frags held in registers for the whole sweep: col n, k = g*4..g*4+3
  s16x4 qfr[2];
#pragma unroll
  for (int nf = 0; nf < 2; ++nf)
    qfr[nf] = *(const s16x4*)(qbase + (size_t)(n0 + wave * 32 + nf * 16 + r) * 16 + g * 4);

  f32x4 oacc[4][2];  // [vf][nf]: O^T frag, col n = lane&15, row v = g*4+i
#pragma unroll
  for (int vf = 0; vf < 4; ++vf)
#pragma unroll
    for (int nf = 0; nf < 2; ++nf)
#pragma unroll
      for (int i = 0; i < 4; ++i) oacc[vf][nf][i] = 0.f;

  for (int m0 = 0; m0 < 2048; m0 += 64) {
    __syncthreads();
    {  // stage K tile 64x16: one 8B chunk per thread
      const int row = tid >> 2, c4 = (tid & 3) * 4;
      *(s16x4*)(&Ks[row][c4]) = *(const s16x4*)(kbase + (size_t)(m0 + row) * 16 + c4);
    }
    if (tid < 64) Zs[tid] = zbase[m0 + tid];
#pragma unroll
    for (int p = 0; p < 2; ++p) {  // stage V^T tile 64v x 64m (straight copy)
      const int ch = p * 256 + tid;
      const int v = ch >> 3, c8 = (ch & 7) * 8;
      s16x8 raw = *(const s16x8*)(vbase + (size_t)v * 2048 + m0 + c8);
      *(s16x8*)(&Vs[v][c8]) = raw;
    }
    __syncthreads();

    s16x4 kfr[4], va[4][4];
#pragma unroll
    for (int mf = 0; mf < 4; ++mf) kfr[mf] = *(const s16x4*)(&Ks[mf * 16 + r][g * 4]);
#pragma unroll
    for (int vf = 0; vf < 4; ++vf)
#pragma unroll
      for (int mf = 0; mf < 4; ++mf)
        va[vf][mf] = *(const s16x4*)(&Vs[vf * 16 + r][mf * 16 + g * 4]);

#pragma unroll
    for (int nf = 0; nf < 2; ++nf) {
      s16x4 pb[4];
#pragma unroll
      for (int mf = 0; mf < 4; ++mf) {
        f32x4 st; st[0] = 0.f; st[1] = 0.f; st[2] = 0.f; st[3] = 0.f;
        st = mfma16(kfr[mf], qfr[nf], st);
        union { s16x4 v; u16 e[4]; } p;
#pragma unroll
        for (int i = 0; i < 4; ++i) {
          float pv = __expf(st[i] * SCALE) * Zs[mf * 16 + g * 4 + i];
          p.e[i] = f2bf(pv);
        }
        pb[mf] = p.v;
      }
#pragma unroll
      for (int vf = 0; vf < 4; ++vf)
#pragma unroll
        for (int mf = 0; mf < 4; ++mf)
          oacc[vf][nf] = mfma16(va[vf][mf], pb[mf], oacc[vf][nf]);
    }
  }
  // epilogue: lane writes (n fixed, 4 consecutive v) per frag
#pragma unroll
  for (int nf = 0; nf < 2; ++nf) {
    const int n = n0 + wave * 32 + nf * 16 + r;
#pragma unroll
    for (int vf = 0; vf < 4; ++vf) {
      ushort4 o;
      o.x = f2bf(oacc[vf][nf][0]); o.y = f2bf(oacc[vf][nf][1]);
      o.z = f2bf(oacc[vf][nf][2]); o.w = f2bf(oacc[vf][nf][3]);
      *(ushort4*)(obase + (size_t)n * 64 + vf * 16 + g * 4) = o;
    }
  }
}

// ---------------------------------------------------------------------------
// k_out: out[4096 x 1024] = Oh(bn x hv) @ wo^T, f32 output.
// Same structure as k_qkv; BK=64 == one head, so A row-slices are contiguous.
// ---------------------------------------------------------------------------
__global__ __launch_bounds__(256) void k_out(
    const u16* __restrict__ Oh, const u16* __restrict__ wo,
    float* __restrict__ out) {
  __shared__ __align__(16) u16 As[128][72];
  __shared__ __align__(16) u16 Bs[64][72];
  const int tid = threadIdx.x;
  const int wave = tid >> 6, lane = tid & 63;
  const int g = lane >> 4, r = lane & 15;
  const int wr = wave >> 1, wc = wave & 1;
  const int r0 = blockIdx.y * 128;
  const int c0 = blockIdx.x * 64;

  f32x4 acc[4][2];
#pragma unroll
  for (int mi = 0; mi < 4; ++mi)
#pragma unroll
    for (int ni = 0; ni < 2; ++ni)
#pragma unroll
      for (int i = 0; i < 4; ++i) acc[mi][ni][i] = 0.f;

  for (int k0 = 0; k0 < 1024; k0 += 64) {
    const int h = k0 >> 6;
    __syncthreads();
#pragma unroll
    for (int p = 0; p < 4; ++p) {  // A: Oh rows (b,n), k-slice = head h
      const int ch = p * 256 + tid;
      const int row = ch >> 3, c8 = (ch & 7) * 8;
      const int R = r0 + row, b = R >> 11, n = R & 2047;
      s16x8 v = *(const s16x8*)(Oh + (((size_t)b * 16 + h) * 2048 + n) * 64 + c8);
      *(s16x8*)(&As[row][c8]) = v;
    }
#pragma unroll
    for (int p = 0; p < 2; ++p) {  // B: wo rows d
      const int ch = p * 256 + tid;
      const int row = ch >> 3, c8 = (ch & 7) * 8;
      s16x8 v = *(const s16x8*)(wo + (size_t)(c0 + row) * 1024 + k0 + c8);
      *(s16x8*)(&Bs[row][c8]) = v;
    }
    __syncthreads();
#pragma unroll
    for (int kf = 0; kf < 2; ++kf) {
      s16x8 a[4], b[2];
#pragma unroll
      for (int mi = 0; mi < 4; ++mi)
        a[mi] = *(const s16x8*)(&As[wr * 64 + mi * 16 + r][kf * 32 + g * 8]);
#pragma unroll
      for (int ni = 0; ni < 2; ++ni)
        b[ni] = *(const s16x8*)(&Bs[wc * 32 + ni * 16 + r][kf * 32 + g * 8]);
#pragma unroll
      for (int mi = 0; mi < 4; ++mi)
#pragma unroll
        for (int ni = 0; ni < 2; ++ni)
          acc[mi][ni] = __builtin_amdgcn_mfma_f32_16x16x32_bf16(a[mi], b[ni], acc[mi][ni], 0, 0, 0);
    }
  }
#pragma unroll
  for (int ni = 0; ni < 2; ++ni) {
    const int d = c0 + wc * 32 + ni * 16 + r;
#pragma unroll
    for (int mi = 0; mi < 4; ++mi) {
      const int rowb = r0 + wr * 64 + mi * 16 + g * 4;
#pragma unroll
      for (int i = 0; i < 4; ++i)
        out[(size_t)(rowb + i) * 1024 + d] = acc[mi][ni][i];
    }
  }
}

// ---------------------------------------------------------------------------
extern "C" void kernel_launch(void* const* d_in, const int* in_sizes, int n_in,
                              void* d_out, int out_size, void* d_ws, size_t ws_size,
                              hipStream_t stream) {
  (void)in_sizes; (void)n_in; (void)out_size; (void)ws_size;
  const float* x  = (const float*)d_in[0];
  const float* qp = (const float*)d_in[1];
  const float* kp = (const float*)d_in[2];
  const float* vp = (const float*)d_in[3];
  const float* op = (const float*)d_in[4];
  float* out = (float*)d_out;
  char* ws = (char*)d_ws;

  u16* xb = (u16*)(ws + OFF_XB);
  u16* Wb = (u16*)(ws + OFF_WB);
  u16* wo = (u16*)(ws + OFF_WO);
  u16* Qt = (u16*)(ws + OFF_QT);
  u16* Kh = (u16*)(ws + OFF_KH);
  u16* Vt = (u16*)(ws + OFF_VT);
  float* Zi = (float*)(ws + OFF_ZI);
  u16* Oh = (u16*)(ws + OFF_OH);

  k_cvt<<<3328, 256, 0, stream>>>(x, qp, kp, vp, op, xb, Wb, wo);
  k_qkv<<<dim3(24, 32), 256, 0, stream>>>(xb, Wb, Qt, Kh, Vt);
  k_colsum<<<dim3(32, 16, 2), 256, 0, stream>>>(Qt, Kh, Zi);
  k_attn<<<dim3(16, 16, 2), 256, 0, stream>>>(Qt, Kh, Vt, Zi, Oh);
  k_out<<<dim3(16, 32), 256, 0, stream>>>(Oh, wo, out);
}

// Round 5
// 120.551 us; speedup vs baseline: 6.6192x; 1.2563x over previous
//
#include <hip/hip_runtime.h>

// MultiHeadAttention (faithful-to-bug variant), round 4.
//   Qt[b,n,h,k] = sum_d x[b,n,d] * qp[k,h,d]   (mislabeled-einsum swap)
//   S = Qt·K^T per head ; softmax over n (axis=1 -> COLUMN softmax)
//   O = A·V ; out = O @ op
// vs round 3 (replay-divergent): removed the two replay-hazard constructs —
//   (1) k_colsum no longer scales Vt in place; it writes a separate Zi buffer
//       (no persistent-state RMW anywhere in the pipeline);
//   (2) k_attn LDS union removed; Ks/Vs/Zs/comb are disjoint arrays.
// Kept: 8-wave m-split k_attn, exp2-prescaled Qt, cvt_pk packing,
// global_load_lds w16 staging in k_qkv/k_out (m97 pattern).

typedef float f32x4 __attribute__((ext_vector_type(4)));
typedef short s16x4 __attribute__((ext_vector_type(4)));
typedef short s16x8 __attribute__((ext_vector_type(8)));
typedef unsigned short u16;

namespace {
constexpr float C2 = 0.36067376022224085f;  // (1/sqrt(16)) * log2(e)

// workspace byte offsets (16B aligned) — identical footprint to round 1 (passed)
constexpr size_t OFF_XB = 0;                                  // xb [4096][1024] bf16
constexpr size_t OFF_WB = OFF_XB + (size_t)4096 * 1024 * 2;   // Wb [1536][1024] bf16
constexpr size_t OFF_WO = OFF_WB + (size_t)1536 * 1024 * 2;   // wo [1024][1024] bf16
constexpr size_t OFF_QT = OFF_WO + (size_t)1024 * 1024 * 2;   // Qt [2][16][2048][16] (pre-scaled)
constexpr size_t OFF_KH = OFF_QT + (size_t)2 * 16 * 2048 * 16 * 2;
constexpr size_t OFF_VT = OFF_KH + (size_t)2 * 16 * 2048 * 16 * 2;  // Vt [2][16][64][2048]
constexpr size_t OFF_ZI = OFF_VT + (size_t)2 * 16 * 64 * 2048 * 2;  // Zi [2][16][2048] f32
constexpr size_t OFF_OH = OFF_ZI + (size_t)2 * 16 * 2048 * 4;       // Oh [2][16][2048][64]
}  // namespace

__device__ __forceinline__ u16 f2bf(float f) {  // RNE f32->bf16
  union { float f; unsigned u; } v; v.f = f;
  return (u16)((v.u + 0x7FFF + ((v.u >> 16) & 1)) >> 16);
}
__device__ __forceinline__ unsigned cvtpk(float lo, float hi) {  // T12 recipe
  unsigned d;
  asm("v_cvt_pk_bf16_f32 %0, %1, %2" : "=v"(d) : "v"(lo), "v"(hi));
  return d;
}
__device__ __forceinline__ float fexp2(float x) {
#if __has_builtin(__builtin_amdgcn_exp2f)
  return __builtin_amdgcn_exp2f(x);
#else
  return exp2f(x);
#endif
}
__device__ __forceinline__ f32x4 mfma16(s16x4 a, s16x4 b, f32x4 c) {
#if __has_builtin(__builtin_amdgcn_mfma_f32_16x16x16_bf16)
  return __builtin_amdgcn_mfma_f32_16x16x16_bf16(a, b, c, 0, 0, 0);
#elif __has_builtin(__builtin_amdgcn_mfma_f32_16x16x16bf16_1k)
  return __builtin_amdgcn_mfma_f32_16x16x16bf16_1k(a, b, c, 0, 0, 0);
#else
  f32x4 d;
  asm volatile("v_mfma_f32_16x16x16_bf16 %0, %1, %2, %3"
               : "=v"(d) : "v"(a), "v"(b), "v"(c));
  return d;
#endif
}
__device__ __forceinline__ void gl16(const void* g, void* l) {  // 16B global->LDS
  __builtin_amdgcn_global_load_lds(
      (const __attribute__((address_space(1))) void*)g,
      (__attribute__((address_space(3))) void*)l, 16, 0, 0);
}

// ---------------------------------------------------------------------------
// k_cvt: f32 -> bf16; packs Wb rows [qp permuted | kp | vp], wo = op.
// ---------------------------------------------------------------------------
__global__ __launch_bounds__(256) void k_cvt(
    const float* __restrict__ x, const float* __restrict__ qp,
    const float* __restrict__ kp, const float* __restrict__ vp,
    const float* __restrict__ op, u16* __restrict__ xb,
    u16* __restrict__ Wb, u16* __restrict__ wo) {
  const int c = blockIdx.x * 256 + threadIdx.x;
  const int XC = (4096 * 1024) / 8, WC = (1536 * 1024) / 8, OC = (1024 * 1024) / 8;
  const float* src; u16* dst;
  if (c < XC) {
    src = x + (size_t)c * 8; dst = xb + (size_t)c * 8;
  } else if (c < XC + WC) {
    const int cc = c - XC;
    const int row = cc >> 7, col = cc & 127;
    if (row < 256) {
      const int h = row >> 4, k = row & 15;
      src = qp + (size_t)(k * 16 + h) * 1024 + col * 8;  // swapped einsum
    } else if (row < 512) {
      src = kp + (size_t)(row - 256) * 1024 + col * 8;
    } else {
      src = vp + (size_t)(row - 512) * 1024 + col * 8;
    }
    dst = Wb + (size_t)cc * 8;
  } else if (c < XC + WC + OC) {
    const int cc = c - XC - WC;
    src = op + (size_t)cc * 8; dst = wo + (size_t)cc * 8;
  } else {
    return;
  }
  float4 lo = *(const float4*)(src);
  float4 hi = *(const float4*)(src + 4);
  union { s16x8 v; unsigned w[4]; } o;
  o.w[0] = cvtpk(lo.x, lo.y); o.w[1] = cvtpk(lo.z, lo.w);
  o.w[2] = cvtpk(hi.x, hi.y); o.w[3] = cvtpk(hi.z, hi.w);
  *(s16x8*)dst = o.v;
}

// ---------------------------------------------------------------------------
// k_qkv: C[4096 x 1536] = xb @ Wb^T. 128x64 tile, BK=64, 4 waves (2x2),
// global_load_lds w16 into LINEAR LDS (m97 structure).
// Epilogue: Qt (scaled by C2) / Kh / Vt (transposed per head).
// ---------------------------------------------------------------------------
__global__ __launch_bounds__(256) void k_qkv(
    const u16* __restrict__ xb, const u16* __restrict__ Wb,
    u16* __restrict__ Qt, u16* __restrict__ Kh, u16* __restrict__ Vt) {
  __shared__ __align__(16) u16 As[128][64];
  __shared__ __align__(16) u16 Bs[64][64];
  const int tid = threadIdx.x;
  const int wave = tid >> 6, lane = tid & 63;
  const int g = lane >> 4, r = lane & 15;
  const int wr = wave >> 1, wc = wave & 1;
  const int r0 = blockIdx.y * 128, c0 = blockIdx.x * 64;
  const int wbase = tid & 192;

  f32x4 acc[4][2];
#pragma unroll
  for (int mi = 0; mi < 4; ++mi)
#pragma unroll
    for (int ni = 0; ni < 2; ++ni)
#pragma unroll
      for (int i = 0; i < 4; ++i) acc[mi][ni][i] = 0.f;

  for (int k0 = 0; k0 < 1024; k0 += 64) {
    __syncthreads();
#pragma unroll
    for (int p = 0; p < 4; ++p) {  // A: 128x64 = 1024 chunks
      const int idx = p * 256 + tid;
      gl16(xb + (size_t)(r0 + (idx >> 3)) * 1024 + k0 + (idx & 7) * 8,
           (char*)As + (size_t)(p * 256 + wbase) * 16);
    }
#pragma unroll
    for (int p = 0; p < 2; ++p) {  // B: 64x64 = 512 chunks
      const int idx = p * 256 + tid;
      gl16(Wb + (size_t)(c0 + (idx >> 3)) * 1024 + k0 + (idx & 7) * 8,
           (char*)Bs + (size_t)(p * 256 + wbase) * 16);
    }
    __syncthreads();
#pragma unroll
    for (int kf = 0; kf < 2; ++kf) {
      s16x8 a[4], b[2];
#pragma unroll
      for (int mi = 0; mi < 4; ++mi)
        a[mi] = *(const s16x8*)(&As[wr * 64 + mi * 16 + r][kf * 32 + g * 8]);
#pragma unroll
      for (int ni = 0; ni < 2; ++ni)
        b[ni] = *(const s16x8*)(&Bs[wc * 32 + ni * 16 + r][kf * 32 + g * 8]);
#pragma unroll
      for (int mi = 0; mi < 4; ++mi)
#pragma unroll
        for (int ni = 0; ni < 2; ++ni)
          acc[mi][ni] = __builtin_amdgcn_mfma_f32_16x16x32_bf16(a[mi], b[ni], acc[mi][ni], 0, 0, 0);
    }
  }
#pragma unroll
  for (int ni = 0; ni < 2; ++ni) {
    const int c = c0 + wc * 32 + ni * 16 + r;
#pragma unroll
    for (int mi = 0; mi < 4; ++mi) {
      const int rowb = r0 + wr * 64 + mi * 16 + g * 4;
      const int b = rowb >> 11, n = rowb & 2047;
      if (c < 256) {  // Qt, pre-scaled for exp2-direct softmax
        const int h = c >> 4, kk = c & 15;
        u16* p = Qt + (((size_t)b * 16 + h) * 2048 + n) * 16 + kk;
        p[0]  = f2bf(acc[mi][ni][0] * C2);
        p[16] = f2bf(acc[mi][ni][1] * C2);
        p[32] = f2bf(acc[mi][ni][2] * C2);
        p[48] = f2bf(acc[mi][ni][3] * C2);
      } else if (c < 512) {
        const int cc = c - 256;
        const int h = cc >> 4, kk = cc & 15;
        u16* p = Kh + (((size_t)b * 16 + h) * 2048 + n) * 16 + kk;
        p[0]  = f2bf(acc[mi][ni][0]);
        p[16] = f2bf(acc[mi][ni][1]);
        p[32] = f2bf(acc[mi][ni][2]);
        p[48] = f2bf(acc[mi][ni][3]);
      } else {
        const int cc = c - 512;
        const int h = cc >> 6, v = cc & 63;
        ushort4 o;
        o.x = f2bf(acc[mi][ni][0]); o.y = f2bf(acc[mi][ni][1]);
        o.z = f2bf(acc[mi][ni][2]); o.w = f2bf(acc[mi][ni][3]);
        *(ushort4*)(Vt + (((size_t)b * 16 + h) * 64 + v) * 2048 + n) = o;
      }
    }
  }
}

// ---------------------------------------------------------------------------
// k_colsum: Zi[b,h,m] = 1 / sum_n exp2(S'[n,m])  (Qt pre-scaled by C2).
// No in-place mutation of any buffer.
// ---------------------------------------------------------------------------
__global__ __launch_bounds__(256) void k_colsum(
    const u16* __restrict__ Qt, const u16* __restrict__ Kh,
    float* __restrict__ Zi) {
  const int m0 = blockIdx.x * 64;
  const int bh = blockIdx.z * 16 + blockIdx.y;
  const u16* qbase = Qt + (size_t)bh * 2048 * 16;
  const u16* kbase = Kh + (size_t)bh * 2048 * 16;
  __shared__ __align__(16) u16 Ks[64][20];
  __shared__ __align__(16) u16 Qs[128][20];
  __shared__ float Zp[4][64];
  const int tid = threadIdx.x;
  const int wave = tid >> 6, lane = tid & 63;
  const int g = lane >> 4, r = lane & 15;

  {  // stage K tile once
    const int row = tid >> 2, c4 = (tid & 3) * 4;
    *(s16x4*)(&Ks[row][c4]) = *(const s16x4*)(kbase + (size_t)(m0 + row) * 16 + c4);
  }
  __syncthreads();
  s16x4 afr[4];
#pragma unroll
  for (int mf = 0; mf < 4; ++mf) afr[mf] = *(const s16x4*)(&Ks[mf * 16 + r][g * 4]);

  float z[4][4];
#pragma unroll
  for (int mf = 0; mf < 4; ++mf)
#pragma unroll
    for (int i = 0; i < 4; ++i) z[mf][i] = 0.f;

  for (int n0 = 0; n0 < 2048; n0 += 128) {
    __syncthreads();
#pragma unroll
    for (int p = 0; p < 2; ++p) {
      const int ch = p * 256 + tid;
      const int row = ch >> 2, c4 = (ch & 3) * 4;
      *(s16x4*)(&Qs[row][c4]) = *(const s16x4*)(qbase + (size_t)(n0 + row) * 16 + c4);
    }
    __syncthreads();
#pragma unroll
    for (int nf = 0; nf < 2; ++nf) {
      s16x4 bfr = *(const s16x4*)(&Qs[wave * 32 + nf * 16 + r][g * 4]);
#pragma unroll
      for (int mf = 0; mf < 4; ++mf) {
        f32x4 st; st[0] = 0.f; st[1] = 0.f; st[2] = 0.f; st[3] = 0.f;
        st = mfma16(afr[mf], bfr, st);
#pragma unroll
        for (int i = 0; i < 4; ++i) z[mf][i] += fexp2(st[i]);
      }
    }
  }
#pragma unroll
  for (int mf = 0; mf < 4; ++mf)
#pragma unroll
    for (int i = 0; i < 4; ++i) {
      float v = z[mf][i];
      v += __shfl_xor(v, 1); v += __shfl_xor(v, 2);
      v += __shfl_xor(v, 4); v += __shfl_xor(v, 8);
      z[mf][i] = v;
    }
  if (r == 0) {
#pragma unroll
    for (int mf = 0; mf < 4; ++mf)
#pragma unroll
      for (int i = 0; i < 4; ++i) Zp[wave][mf * 16 + g * 4 + i] = z[mf][i];
  }
  __syncthreads();
  if (tid < 64) {
    Zi[(size_t)bh * 2048 + m0 + tid] =
        1.0f / (Zp[0][tid] + Zp[1][tid] + Zp[2][tid] + Zp[3][tid]);
  }
}

// ---------------------------------------------------------------------------
// k_attn: 8 waves / 512 threads; waves 0-3 sweep m in [0,1024), waves 4-7
// [1024,2048) (same n-range); partial O^T combined via a DEDICATED f32 LDS
// buffer (no aliasing). P = exp2(S') * Zi[m] packed to bf16 in-register.
// ---------------------------------------------------------------------------
__global__ __launch_bounds__(512) void k_attn(
    const u16* __restrict__ Qt, const u16* __restrict__ Kh,
    const u16* __restrict__ Vt, const float* __restrict__ Zi,
    u16* __restrict__ Oh) {
  const int n0 = blockIdx.x * 128;
  const int bh = blockIdx.z * 16 + blockIdx.y;
  const u16* qbase = Qt + (size_t)bh * 2048 * 16;
  const u16* kbase = Kh + (size_t)bh * 2048 * 16;
  const u16* vbase = Vt + (size_t)bh * 64 * 2048;
  const float* zbase = Zi + (size_t)bh * 2048;
  u16* obase = Oh + (size_t)bh * 2048 * 64;

  __shared__ __align__(16) u16 Ks[2][64][20];
  __shared__ __align__(16) u16 Vs[2][64][72];
  __shared__ float Zs[2][64];
  __shared__ float comb[4][32][68];

  const int tid = threadIdx.x;
  const int wave = tid >> 6, lane = tid & 63;
  const int g = lane >> 4, r = lane & 15;
  const int half = wave >> 2, wq = wave & 3;

  s16x4 qfr[2];
#pragma unroll
  for (int nf = 0; nf < 2; ++nf)
    qfr[nf] = *(const s16x4*)(qbase + (size_t)(n0 + wq * 32 + nf * 16 + r) * 16 + g * 4);

  f32x4 oacc[4][2];
#pragma unroll
  for (int vf = 0; vf < 4; ++vf)
#pragma unroll
    for (int nf = 0; nf < 2; ++nf)
#pragma unroll
      for (int i = 0; i < 4; ++i) oacc[vf][nf][i] = 0.f;

  const int ks_hk = tid >> 8, ks_rem = tid & 255;
  const int ks_row = ks_rem >> 2, ks_c4 = (ks_rem & 3) * 4;

  for (int t = 0; t < 16; ++t) {
    __syncthreads();
    // stage K tiles for both halves: 2 x 64 x 16 = 512 s16x4 chunks
    *(s16x4*)(&Ks[ks_hk][ks_row][ks_c4]) =
        *(const s16x4*)(kbase + (size_t)(ks_hk * 1024 + t * 64 + ks_row) * 16 + ks_c4);
    // stage V tiles for both halves: 2 x 64 x 64 = 1024 s16x8 chunks
#pragma unroll
    for (int p = 0; p < 2; ++p) {
      const int q = p * 512 + tid;
      const int hv = q >> 9, rem = q & 511;
      const int v = rem >> 3, c8 = (rem & 7) * 8;
      *(s16x8*)(&Vs[hv][v][c8]) =
          *(const s16x8*)(vbase + (size_t)v * 2048 + hv * 1024 + t * 64 + c8);
    }
    // stage Zi for both halves' m-tiles
    if (tid < 128) Zs[tid >> 6][tid & 63] = zbase[(tid >> 6) * 1024 + t * 64 + (tid & 63)];
    __syncthreads();

    s16x4 kfr[4], va[4][4];
#pragma unroll
    for (int mf = 0; mf < 4; ++mf)
      kfr[mf] = *(const s16x4*)(&Ks[half][mf * 16 + r][g * 4]);
#pragma unroll
    for (int vf = 0; vf < 4; ++vf)
#pragma unroll
      for (int mf = 0; mf < 4; ++mf)
        va[vf][mf] = *(const s16x4*)(&Vs[half][vf * 16 + r][mf * 16 + g * 4]);

#pragma unroll
    for (int nf = 0; nf < 2; ++nf) {
      s16x4 pb[4];
#pragma unroll
      for (int mf = 0; mf < 4; ++mf) {
        f32x4 st; st[0] = 0.f; st[1] = 0.f; st[2] = 0.f; st[3] = 0.f;
        st = mfma16(kfr[mf], qfr[nf], st);
        union { s16x4 v4; unsigned w[2]; } pk;
        const int mloc = mf * 16 + g * 4;
        pk.w[0] = cvtpk(fexp2(st[0]) * Zs[half][mloc + 0],
                        fexp2(st[1]) * Zs[half][mloc + 1]);
        pk.w[1] = cvtpk(fexp2(st[2]) * Zs[half][mloc + 2],
                        fexp2(st[3]) * Zs[half][mloc + 3]);
        pb[mf] = pk.v4;
      }
#pragma unroll
      for (int vf = 0; vf < 4; ++vf)
#pragma unroll
        for (int mf = 0; mf < 4; ++mf)
          oacc[vf][nf] = mfma16(va[vf][mf], pb[mf], oacc[vf][nf]);
    }
  }

  __syncthreads();
  if (half == 1) {
#pragma unroll
    for (int nf = 0; nf < 2; ++nf)
#pragma unroll
      for (int vf = 0; vf < 4; ++vf)
#pragma unroll
        for (int i = 0; i < 4; ++i)
          comb[wq][nf * 16 + r][vf * 16 + g * 4 + i] = oacc[vf][nf][i];
  }
  __syncthreads();
  if (half == 0) {
#pragma unroll
    for (int nf = 0; nf < 2; ++nf)
#pragma unroll
      for (int vf = 0; vf < 4; ++vf)
#pragma unroll
        for (int i = 0; i < 4; ++i)
          oacc[vf][nf][i] += comb[wq][nf * 16 + r][vf * 16 + g * 4 + i];
#pragma unroll
    for (int nf = 0; nf < 2; ++nf) {
      const int n = n0 + wq * 32 + nf * 16 + r;
#pragma unroll
      for (int vf = 0; vf < 4; ++vf) {
        union { s16x4 v4; unsigned w[2]; } pk;
        pk.w[0] = cvtpk(oacc[vf][nf][0], oacc[vf][nf][1]);
        pk.w[1] = cvtpk(oacc[vf][nf][2], oacc[vf][nf][3]);
        *(s16x4*)(obase + (size_t)n * 64 + vf * 16 + g * 4) = pk.v4;
      }
    }
  }
}

// ---------------------------------------------------------------------------
// k_out: out[4096 x 1024] = Oh(bn x hv) @ wo^T, f32 out. m97-style staging.
// ---------------------------------------------------------------------------
__global__ __launch_bounds__(256) void k_out(
    const u16* __restrict__ Oh, const u16* __restrict__ wo,
    float* __restrict__ out) {
  __shared__ __align__(16) u16 As[128][64];
  __shared__ __align__(16) u16 Bs[64][64];
  const int tid = threadIdx.x;
  const int wave = tid >> 6, lane = tid & 63;
  const int g = lane >> 4, r = lane & 15;
  const int wr = wave >> 1, wc = wave & 1;
  const int r0 = blockIdx.y * 128, c0 = blockIdx.x * 64;
  const int wbase = tid & 192;

  f32x4 acc[4][2];
#pragma unroll
  for (int mi = 0; mi < 4; ++mi)
#pragma unroll
    for (int ni = 0; ni < 2; ++ni)
#pragma unroll
      for (int i = 0; i < 4; ++i) acc[mi][ni][i] = 0.f;

  for (int k0 = 0; k0 < 1024; k0 += 64) {
    const int h = k0 >> 6;
    __syncthreads();
#pragma unroll
    for (int p = 0; p < 4; ++p) {  // A: Oh rows (b,n), k-slice = head h
      const int idx = p * 256 + tid;
      const int row = idx >> 3, c8 = (idx & 7) * 8;
      const int R = r0 + row, b = R >> 11, n = R & 2047;
      gl16(Oh + (((size_t)b * 16 + h) * 2048 + n) * 64 + c8,
           (char*)As + (size_t)(p * 256 + wbase) * 16);
    }
#pragma unroll
    for (int p = 0; p < 2; ++p) {  // B: wo rows d
      const int idx = p * 256 + tid;
      gl16(wo + (size_t)(c0 + (idx >> 3)) * 1024 + k0 + (idx & 7) * 8,
           (char*)Bs + (size_t)(p * 256 + wbase) * 16);
    }
    __syncthreads();
#pragma unroll
    for (int kf = 0; kf < 2; ++kf) {
      s16x8 a[4], b[2];
#pragma unroll
      for (int mi = 0; mi < 4; ++mi)
        a[mi] = *(const s16x8*)(&As[wr * 64 + mi * 16 + r][kf * 32 + g * 8]);
#pragma unroll
      for (int ni = 0; ni < 2; ++ni)
        b[ni] = *(const s16x8*)(&Bs[wc * 32 + ni * 16 + r][kf * 32 + g * 8]);
#pragma unroll
      for (int mi = 0; mi < 4; ++mi)
#pragma unroll
        for (int ni = 0; ni < 2; ++ni)
          acc[mi][ni] = __builtin_amdgcn_mfma_f32_16x16x32_bf16(a[mi], b[ni], acc[mi][ni], 0, 0, 0);
    }
  }
#pragma unroll
  for (int ni = 0; ni < 2; ++ni) {
    const int d = c0 + wc * 32 + ni * 16 + r;
#pragma unroll
    for (int mi = 0; mi < 4; ++mi) {
      const int rowb = r0 + wr * 64 + mi * 16 + g * 4;
#pragma unroll
      for (int i = 0; i < 4; ++i)
        out[(size_t)(rowb + i) * 1024 + d] = acc[mi][ni][i];
    }
  }
}

// ---------------------------------------------------------------------------
extern "C" void kernel_launch(void* const* d_in, const int* in_sizes, int n_in,
                              void* d_out, int out_size, void* d_ws, size_t ws_size,
                              hipStream_t stream) {
  (void)in_sizes; (void)n_in; (void)out_size; (void)ws_size;
  const float* x  = (const float*)d_in[0];
  const float* qp = (const float*)d_in[1];
  const float* kp = (const float*)d_in[2];
  const float* vp = (const float*)d_in[3];
  const float* op = (const float*)d_in[4];
  float* out = (float*)d_out;
  char* ws = (char*)d_ws;

  u16* xb = (u16*)(ws + OFF_XB);
  u16* Wb = (u16*)(ws + OFF_WB);
  u16* wo = (u16*)(ws + OFF_WO);
  u16* Qt = (u16*)(ws + OFF_QT);
  u16* Kh = (u16*)(ws + OFF_KH);
  u16* Vt = (u16*)(ws + OFF_VT);
  float* Zi = (float*)(ws + OFF_ZI);
  u16* Oh = (u16*)(ws + OFF_OH);

  k_cvt<<<3328, 256, 0, stream>>>(x, qp, kp, vp, op, xb, Wb, wo);
  k_qkv<<<dim3(24, 32), 256, 0, stream>>>(xb, Wb, Qt, Kh, Vt);
  k_colsum<<<dim3(32, 16, 2), 256, 0, stream>>>(Qt, Kh, Zi);
  k_attn<<<dim3(16, 16, 2), 512, 0, stream>>>(Qt, Kh, Vt, Zi, Oh);
  k_out<<<dim3(16, 32), 256, 0, stream>>>(Oh, wo, out);
}